// Round 12
// baseline (122.072 us; speedup 1.0000x reference)
//
#include <hip/hip_runtime.h>

#define HW    262144      // 512*512
#define BNUM  4
#define NC    33          // labels 0..32
#define NI    32          // instance channels

#define NB     1024       // t-space bins
#define BSCALE 64.0f      // NB / TMAX (TMAX = 16)
#define EG     4096       // e-grid bins in scan
#define ESCALE 2048.0f    // EG / 2.0

typedef unsigned long long ull;

// ws layout in 32-bit words:
//   [0 .. 8192)    t-hist: u64[NB] per sample (sample s at ull index s*NB)
//   [8192..8196)   cntB[s]  hist arrival counters
//   [8196]         cntF     finalize counter
//   [8200..8204)   fin[s]   per-sample losses
//   [8208.. )      partials float[s][128][168]
#define W_CNTB 8192
#define W_CNTF 8196
#define W_FINL 8200
#define W_PART 8208
#define PJ 168            // padded words per block slot (165 used)
#define PS (128 * PJ)     // words per sample

// ---------------- Pass A: per-instance stats -> deterministic partials.
// Also zeroes t-hist + counters (no separate memset dispatch).
__global__ void __launch_bounds__(256) stats_kernel(
    const float* __restrict__ emb, const float* __restrict__ sig,
    const int* __restrict__ gt, float* __restrict__ ws) {
  int s = blockIdx.y;          // sample
  int j = blockIdx.x;          // 0..127 block within sample
  int t = threadIdx.x;
  int w = t >> 6;
  __shared__ float acc[4][165];   // [wave][f*33+n], f: e0,e1,ss,ss2,cnt
  int bid = s * 128 + j;          // 0..511
  unsigned* wsu = (unsigned*)ws;
  if (t < 16) {
    wsu[bid * 16 + t] = 0u;                  // 512*16 = 8192 words of t-hist
    if (bid == 0) wsu[8192 + t] = 0u;        // counters + fin
  }
  for (int k = t; k < 4 * 165; k += 256) ((float*)acc)[k] = 0.f;
  __syncthreads();
  const float* e0p = emb + (size_t)s * 2 * HW;
  const float* e1p = e0p + HW;
  const float* sp  = sig + (size_t)s * HW;
  const int*   gp  = gt  + (size_t)s * HW;
  #pragma unroll
  for (int i = 0; i < 2; ++i) {
    int idx = j * 2048 + i * 1024 + t * 4;
    int4   lb = *(const int4*)(gp + idx);
    float4 x  = *(const float4*)(e0p + idx);
    float4 y  = *(const float4*)(e1p + idx);
    float4 sg = *(const float4*)(sp + idx);
#define ACC(L, X, Y, SG)                                                   \
    if (L > 0) {                                                           \
      atomicAdd(&acc[w][L], X);        atomicAdd(&acc[w][33 + L], Y);      \
      atomicAdd(&acc[w][66 + L], SG);  atomicAdd(&acc[w][99 + L], (SG)*(SG)); \
      atomicAdd(&acc[w][132 + L], 1.0f);                                   \
    }
    ACC(lb.x, x.x, y.x, sg.x)
    ACC(lb.y, x.y, y.y, sg.y)
    ACC(lb.z, x.z, y.z, sg.z)
    ACC(lb.w, x.w, y.w, sg.w)
#undef ACC
  }
  __syncthreads();
  if (t < 165) {
    float v = acc[0][t] + acc[1][t] + acc[2][t] + acc[3][t];
    ws[W_PART + s * PS + j * PJ + t] = v;   // plain store, unique slot
  }
}

// ---------------- Pass B+C fused: hist (8 px/thread); last block scans.
__global__ void __launch_bounds__(512) hist_scan_kernel(
    const float* __restrict__ emb, const int* __restrict__ gt,
    float* __restrict__ ws, float* __restrict__ out) {
  int s  = blockIdx.y;
  int lb = blockIdx.x;           // 0..63
  __shared__ unsigned hist[EG * 2];   // 32 KB; hist phase uses first NB*4 (16 KB)
  __shared__ float sums[165];
  __shared__ float4 cons[NC];
  __shared__ ull wsum[8];
  __shared__ float red[8];
  __shared__ float vart_s;
  __shared__ int flag;
  int t = threadIdx.x;
  int lane = t & 63, wid = t >> 6;
  for (int k = t; k < NB * 4; k += 512) hist[k] = 0u;
  // sum the 128 per-block partials for this sample (coalesced across t)
  if (t < 165) {
    const float* pp = ws + W_PART + s * PS + t;
    float sum = 0.f;
    #pragma unroll 8
    for (int j = 0; j < 128; ++j) sum += pp[j * PJ];
    sums[t] = sum;
  }
  __syncthreads();
  if (t >= 1 && t < NC) {
    float c = sums[132 + t];
    float4 C;
    if (c > 0.f) {
      float inv = 1.0f / c;
      float c0 = sums[t] * inv, c1 = sums[33 + t] * inv, sgm = sums[66 + t] * inv;
      float Q = 0.5f / (sgm * sgm) * BSCALE;
      C.x = Q; C.y = -2.0f * Q * c0; C.z = -2.0f * Q * c1;
      C.w = Q * (c0 * c0 + c1 * c1);
    } else {
      C.x = 0.f; C.y = 0.f; C.z = 0.f; C.w = (float)NB;  // never bins
    }
    cons[t] = C;
  }
  __syncthreads();
  const float* e0p = emb + (size_t)s * 2 * HW;
  const float* e1p = e0p + HW;
  const int*   gp  = gt  + (size_t)s * HW;
  unsigned* hr = hist + (t & 3);
  #pragma unroll
  for (int half = 0; half < 2; ++half) {
    int idx = lb * 4096 + half * 2048 + t * 4;
    int4   lbl = *(const int4*)(gp + idx);
    float4 px  = *(const float4*)(e0p + idx);
    float4 py  = *(const float4*)(e1p + idx);
    float4 ss;
    ss.x = fmaf(px.x, px.x, py.x * py.x);
    ss.y = fmaf(px.y, px.y, py.y * py.y);
    ss.z = fmaf(px.z, px.z, py.z * py.z);
    ss.w = fmaf(px.w, px.w, py.w * py.w);
    #pragma unroll 4
    for (int n = 1; n <= NI; ++n) {
      float4 C = cons[n];
#define ITEM(P0, P1, SV, L)                                            \
      {                                                                \
        float bf = fmaf(C.x, SV, fmaf(C.y, P0, fmaf(C.z, P1, C.w)));   \
        int ib = (int)bf;                                              \
        bool pos = (L == n);                                           \
        if (pos) ib = min(ib, NB - 1);                                 \
        if (ib < NB) atomicAdd(&hr[ib << 2], pos ? 0x10000u : 1u);     \
      }
      ITEM(px.x, py.x, ss.x, lbl.x)
      ITEM(px.y, py.y, ss.y, lbl.y)
      ITEM(px.z, py.z, ss.z, lbl.z)
      ITEM(px.w, py.w, ss.w, lbl.w)
#undef ITEM
    }
  }
  __syncthreads();
  // flush to the sample's global t-hist (device-scope u64 atomics)
  ull* th = ((ull*)ws) + (size_t)s * NB;
  for (int k = t; k < NB; k += 512) {
    unsigned v = hist[k*4] + hist[k*4+1] + hist[k*4+2] + hist[k*4+3];
    if (v) {
      ull add = ((ull)(v >> 16) << 32) | (v & 0xFFFFu);
      atomicAdd(&th[k], add);
    }
  }
  __syncthreads();
  if (t == 0) {
    __threadfence();   // release our flush before arrival
    flag = (atomicAdd((unsigned*)ws + W_CNTB + s, 1u) == 63u);
  }
  __syncthreads();
  if (!flag) return;

  // ================= scan phase (one block per sample) =================
  unsigned* ep = hist;
  unsigned* en = hist + EG;
  for (int k = t; k < 2 * EG; k += 512) hist[k] = 0u;
  if (wid == 0) {   // pooled variance: vart = S_total * (sum 1/c) / NI
    float S = 0.f, rcp = 0.f;
    if (lane >= 1 && lane < NC) {
      float c = sums[132 + lane];
      if (c > 0.f) {
        float sg = sums[66 + lane] / c;
        S = sums[99 + lane] - c * sg * sg;
        rcp = 1.0f / c;
      }
    }
    for (int o = 32; o; o >>= 1) {
      S   += __shfl_down(S, o);
      rcp += __shfl_down(rcp, o);
    }
    if (lane == 0) vart_s = S * rcp / (float)NI;
  }
  __syncthreads();
  // read global t-hist (atomic reads for cross-XCD coherence), scatter to e-grid
  for (int b = t; b < NB; b += 512) {
    ull v = atomicAdd(&th[b], 0ull);
    unsigned pos = (unsigned)(v >> 32), neg = (unsigned)(v & 0xFFFFFFFFu);
    if (pos | neg) {
      float tc = ((float)b + 0.5f) * (1.0f / BSCALE);
      float ex = __expf(-tc);
      if (pos) {
        float e = 2.0f - 2.0f * ex;
        int k = (int)(e * ESCALE); if (k > EG - 1) k = EG - 1;
        atomicAdd(&ep[k], pos);
      }
      if (neg) {
        float e = 2.0f * ex;
        int k = (int)(e * ESCALE); if (k > EG - 1) k = EG - 1;
        atomicAdd(&en[k], neg);
      }
    }
  }
  __syncthreads();
  const int CH = EG / 512;  // 8
  int j0 = t * CH;
  unsigned np = 0, nn = 0;
  for (int k = 0; k < CH; ++k) {
    int b = EG - 1 - (j0 + k);
    np += ep[b]; nn += en[b];
  }
  ull v = ((ull)np << 32) | (ull)nn;
  ull inc = v;
  for (int o = 1; o < 64; o <<= 1) {
    ull u = __shfl_up(inc, o);
    if (lane >= o) inc += u;
  }
  if (lane == 63) wsum[wid] = inc;
  __syncthreads();
  ull offset = 0, total = 0;
  for (int i = 0; i < 8; ++i) {
    ull xr = wsum[i];
    if (i < wid) offset += xr;
    total += xr;
  }
  ull excl = offset + inc - v;
  float P = (float)(unsigned)(total >> 32);
  unsigned p = (unsigned)(excl >> 32), f = (unsigned)(excl & 0xFFFFFFFFu);
  float jprev = 1.0f - (P - (float)p) / (P + (float)f);
  float contrib = 0.f;
  for (int k = 0; k < CH; ++k) {
    int b = EG - 1 - (j0 + k);
    unsigned ap_ = ep[b], an_ = en[b];
    if (ap_ | an_) {
      p += ap_; f += an_;
      float j = 1.0f - (P - (float)p) / (P + (float)f);
      float e = ((float)b + 0.5f) * (2.0f / EG);
      contrib += e * (j - jprev);
      jprev = j;
    }
  }
  for (int o = 32; o; o >>= 1) contrib += __shfl_down(contrib, o);
  if (lane == 0) red[wid] = contrib;
  __syncthreads();
  if (t == 0) {
    float tot = 0.f;
    for (int i = 0; i < 8; ++i) tot += red[i];
    float loss = tot + vart_s;
    float* fin = ws + W_FINL;
    atomicExch(&fin[s], loss);
    __threadfence();
    unsigned old = atomicAdd((unsigned*)ws + W_CNTF, 1u);
    if (old == BNUM - 1) {
      float a = 0.f;
      for (int i = 0; i < BNUM; ++i) a += atomicAdd(&fin[i], 0.0f);
      out[0] = a * (1.0f / BNUM);
    }
  }
}

extern "C" void kernel_launch(void* const* d_in, const int* in_sizes, int n_in,
                              void* d_out, int out_size, void* d_ws, size_t ws_size,
                              hipStream_t stream) {
  const float* emb = (const float*)d_in[0];   // [4,2,512,512]
  const float* sig = (const float*)d_in[1];   // [4,1,512,512]
  const int*   gt  = (const int*)d_in[2];     // [4,1,512,512]
  float* out = (float*)d_out;
  float* ws  = (float*)d_ws;

  dim3 gA(128, BNUM);
  stats_kernel<<<gA, 256, 0, stream>>>(emb, sig, gt, ws);
  dim3 gB(64, BNUM);
  hist_scan_kernel<<<gB, 512, 0, stream>>>(emb, gt, ws, out);
}

// Round 13
// 117.634 us; speedup vs baseline: 1.0377x; 1.0377x over previous
//
#include <hip/hip_runtime.h>

#define HW    262144      // 512*512
#define BNUM  4
#define NC    33          // labels 0..32
#define NI    32          // instance channels

#define NB     1024       // t-space bins
#define BSCALE 64.0f      // NB / TMAX (TMAX = 16)
#define EG     4096       // e-grid bins in scan
#define ESCALE 2048.0f    // EG / 2.0

typedef unsigned long long ull;

// ws layout in 32-bit words:
//   [0 .. 8192)    t-hist: u64[NB] per sample (sample s at ull index s*NB)
//   [8192..8196)   cntB[s]  hist arrival counters
//   [8196]         cntF     finalize counter
//   [8200..8204)   fin[s]   per-sample losses
//   [8208.. )      partials float[s][128][168]
#define W_CNTB 8192
#define W_CNTF 8196
#define W_FINL 8200
#define W_PART 8208
#define PJ 168            // padded words per block slot (165 used)
#define PS (128 * PJ)     // words per sample

// ---------------- Pass A: per-instance stats -> deterministic partials.
// Also zeroes t-hist + counters (no separate memset dispatch).
__global__ void __launch_bounds__(256) stats_kernel(
    const float* __restrict__ emb, const float* __restrict__ sig,
    const int* __restrict__ gt, float* __restrict__ ws) {
  int s = blockIdx.y;          // sample
  int j = blockIdx.x;          // 0..127 block within sample
  int t = threadIdx.x;
  int w = t >> 6;
  __shared__ float acc[4][165];   // [wave][f*33+n], f: e0,e1,ss,ss2,cnt
  int bid = s * 128 + j;          // 0..511
  unsigned* wsu = (unsigned*)ws;
  if (t < 16) {
    wsu[bid * 16 + t] = 0u;                  // 512*16 = 8192 words of t-hist
    if (bid == 0) wsu[8192 + t] = 0u;        // counters + fin
  }
  for (int k = t; k < 4 * 165; k += 256) ((float*)acc)[k] = 0.f;
  __syncthreads();
  const float* e0p = emb + (size_t)s * 2 * HW;
  const float* e1p = e0p + HW;
  const float* sp  = sig + (size_t)s * HW;
  const int*   gp  = gt  + (size_t)s * HW;
  #pragma unroll
  for (int i = 0; i < 2; ++i) {
    int idx = j * 2048 + i * 1024 + t * 4;
    int4   lb = *(const int4*)(gp + idx);
    float4 x  = *(const float4*)(e0p + idx);
    float4 y  = *(const float4*)(e1p + idx);
    float4 sg = *(const float4*)(sp + idx);
#define ACC(L, X, Y, SG)                                                   \
    if (L > 0) {                                                           \
      atomicAdd(&acc[w][L], X);        atomicAdd(&acc[w][33 + L], Y);      \
      atomicAdd(&acc[w][66 + L], SG);  atomicAdd(&acc[w][99 + L], (SG)*(SG)); \
      atomicAdd(&acc[w][132 + L], 1.0f);                                   \
    }
    ACC(lb.x, x.x, y.x, sg.x)
    ACC(lb.y, x.y, y.y, sg.y)
    ACC(lb.z, x.z, y.z, sg.z)
    ACC(lb.w, x.w, y.w, sg.w)
#undef ACC
  }
  __syncthreads();
  if (t < 165) {
    float v = acc[0][t] + acc[1][t] + acc[2][t] + acc[3][t];
    ws[W_PART + s * PS + j * PJ + t] = v;   // plain store, unique slot
  }
}

// ---------------- Pass B+C fused: hist; last-arriving block per sample scans.
__global__ void __launch_bounds__(512) hist_scan_kernel(
    const float* __restrict__ emb, const int* __restrict__ gt,
    float* __restrict__ ws, float* __restrict__ out) {
  int s  = blockIdx.y;
  int lb = blockIdx.x;           // 0..127
  __shared__ unsigned hist[EG * 2];   // 32 KB; hist phase uses first NB*4 (16 KB)
  __shared__ float sums[165];
  __shared__ float4 cons[NC];
  __shared__ ull wsum[8];
  __shared__ float red[8];
  __shared__ float vart_s;
  __shared__ int flag;
  int t = threadIdx.x;
  int lane = t & 63, wid = t >> 6;
  for (int k = t; k < NB * 4; k += 512) hist[k] = 0u;
  // sum the 128 per-block partials for this sample (coalesced across t)
  if (t < 165) {
    const float* pp = ws + W_PART + s * PS + t;
    float sum = 0.f;
    #pragma unroll 8
    for (int j = 0; j < 128; ++j) sum += pp[j * PJ];
    sums[t] = sum;
  }
  __syncthreads();
  if (t >= 1 && t < NC) {
    float c = sums[132 + t];
    float4 C;
    if (c > 0.f) {
      float inv = 1.0f / c;
      float c0 = sums[t] * inv, c1 = sums[33 + t] * inv, sgm = sums[66 + t] * inv;
      float Q = 0.5f / (sgm * sgm) * BSCALE;
      C.x = Q; C.y = -2.0f * Q * c0; C.z = -2.0f * Q * c1;
      C.w = Q * (c0 * c0 + c1 * c1);
    } else {
      C.x = 0.f; C.y = 0.f; C.z = 0.f; C.w = (float)NB;  // never bins
    }
    cons[t] = C;
  }
  __syncthreads();
  const float* e0p = emb + (size_t)s * 2 * HW;
  const float* e1p = e0p + HW;
  const int*   gp  = gt  + (size_t)s * HW;
  int idx = lb * 2048 + t * 4;
  int4   lbl = *(const int4*)(gp + idx);
  float4 px  = *(const float4*)(e0p + idx);
  float4 py  = *(const float4*)(e1p + idx);
  float4 ss;
  ss.x = fmaf(px.x, px.x, py.x * py.x);
  ss.y = fmaf(px.y, px.y, py.y * py.y);
  ss.z = fmaf(px.z, px.z, py.z * py.z);
  ss.w = fmaf(px.w, px.w, py.w * py.w);
  unsigned* hr = hist + (t & 3);
  #pragma unroll 4
  for (int n = 1; n <= NI; ++n) {
    float4 C = cons[n];
#define ITEM(P0, P1, SV, L)                                            \
    {                                                                  \
      float bf = fmaf(C.x, SV, fmaf(C.y, P0, fmaf(C.z, P1, C.w)));     \
      int ib = (int)bf;                                                \
      bool pos = (L == n);                                             \
      if (pos) ib = min(ib, NB - 1);                                   \
      if (ib < NB) atomicAdd(&hr[ib << 2], pos ? 0x10000u : 1u);       \
    }
    ITEM(px.x, py.x, ss.x, lbl.x)
    ITEM(px.y, py.y, ss.y, lbl.y)
    ITEM(px.z, py.z, ss.z, lbl.z)
    ITEM(px.w, py.w, ss.w, lbl.w)
#undef ITEM
  }
  __syncthreads();
  // flush to the sample's global t-hist (device-scope u64 atomics)
  ull* th = ((ull*)ws) + (size_t)s * NB;
  for (int k = t; k < NB; k += 512) {
    unsigned v = hist[k*4] + hist[k*4+1] + hist[k*4+2] + hist[k*4+3];
    if (v) {
      ull add = ((ull)(v >> 16) << 32) | (v & 0xFFFFu);
      atomicAdd(&th[k], add);
    }
  }
  __syncthreads();
  if (t == 0) {
    __threadfence();   // release our flush before arrival
    flag = (atomicAdd((unsigned*)ws + W_CNTB + s, 1u) == 127u);
  }
  __syncthreads();
  if (!flag) return;

  // ================= scan phase (one block per sample) =================
  unsigned* ep = hist;
  unsigned* en = hist + EG;
  for (int k = t; k < 2 * EG; k += 512) hist[k] = 0u;
  if (wid == 0) {   // pooled variance: vart = S_total * (sum 1/c) / NI
    float S = 0.f, rcp = 0.f;
    if (lane >= 1 && lane < NC) {
      float c = sums[132 + lane];
      if (c > 0.f) {
        float sg = sums[66 + lane] / c;
        S = sums[99 + lane] - c * sg * sg;
        rcp = 1.0f / c;
      }
    }
    for (int o = 32; o; o >>= 1) {
      S   += __shfl_down(S, o);
      rcp += __shfl_down(rcp, o);
    }
    if (lane == 0) vart_s = S * rcp / (float)NI;
  }
  __syncthreads();
  // read global t-hist (atomic reads for cross-XCD coherence), scatter to e-grid
  for (int b = t; b < NB; b += 512) {
    ull v = atomicAdd(&th[b], 0ull);
    unsigned pos = (unsigned)(v >> 32), neg = (unsigned)(v & 0xFFFFFFFFu);
    if (pos | neg) {
      float tc = ((float)b + 0.5f) * (1.0f / BSCALE);
      float ex = __expf(-tc);
      if (pos) {
        float e = 2.0f - 2.0f * ex;
        int k = (int)(e * ESCALE); if (k > EG - 1) k = EG - 1;
        atomicAdd(&ep[k], pos);
      }
      if (neg) {
        float e = 2.0f * ex;
        int k = (int)(e * ESCALE); if (k > EG - 1) k = EG - 1;
        atomicAdd(&en[k], neg);
      }
    }
  }
  __syncthreads();
  const int CH = EG / 512;  // 8
  int j0 = t * CH;
  unsigned np = 0, nn = 0;
  for (int k = 0; k < CH; ++k) {
    int b = EG - 1 - (j0 + k);
    np += ep[b]; nn += en[b];
  }
  ull v = ((ull)np << 32) | (ull)nn;
  ull inc = v;
  for (int o = 1; o < 64; o <<= 1) {
    ull u = __shfl_up(inc, o);
    if (lane >= o) inc += u;
  }
  if (lane == 63) wsum[wid] = inc;
  __syncthreads();
  ull offset = 0, total = 0;
  for (int i = 0; i < 8; ++i) {
    ull xr = wsum[i];
    if (i < wid) offset += xr;
    total += xr;
  }
  ull excl = offset + inc - v;
  float P = (float)(unsigned)(total >> 32);
  unsigned p = (unsigned)(excl >> 32), f = (unsigned)(excl & 0xFFFFFFFFu);
  float jprev = 1.0f - (P - (float)p) / (P + (float)f);
  float contrib = 0.f;
  for (int k = 0; k < CH; ++k) {
    int b = EG - 1 - (j0 + k);
    unsigned ap_ = ep[b], an_ = en[b];
    if (ap_ | an_) {
      p += ap_; f += an_;
      float j = 1.0f - (P - (float)p) / (P + (float)f);
      float e = ((float)b + 0.5f) * (2.0f / EG);
      contrib += e * (j - jprev);
      jprev = j;
    }
  }
  for (int o = 32; o; o >>= 1) contrib += __shfl_down(contrib, o);
  if (lane == 0) red[wid] = contrib;
  __syncthreads();
  if (t == 0) {
    float tot = 0.f;
    for (int i = 0; i < 8; ++i) tot += red[i];
    float loss = tot + vart_s;
    float* fin = ws + W_FINL;
    atomicExch(&fin[s], loss);
    __threadfence();
    unsigned old = atomicAdd((unsigned*)ws + W_CNTF, 1u);
    if (old == BNUM - 1) {
      float a = 0.f;
      for (int i = 0; i < BNUM; ++i) a += atomicAdd(&fin[i], 0.0f);
      out[0] = a * (1.0f / BNUM);
    }
  }
}

extern "C" void kernel_launch(void* const* d_in, const int* in_sizes, int n_in,
                              void* d_out, int out_size, void* d_ws, size_t ws_size,
                              hipStream_t stream) {
  const float* emb = (const float*)d_in[0];   // [4,2,512,512]
  const float* sig = (const float*)d_in[1];   // [4,1,512,512]
  const int*   gt  = (const int*)d_in[2];     // [4,1,512,512]
  float* out = (float*)d_out;
  float* ws  = (float*)d_ws;

  dim3 gA(128, BNUM);
  stats_kernel<<<gA, 256, 0, stream>>>(emb, sig, gt, ws);
  dim3 gB(128, BNUM);
  hist_scan_kernel<<<gB, 512, 0, stream>>>(emb, gt, ws, out);
}